// Round 1
// baseline (2784.942 us; speedup 1.0000x reference)
//
#include <hip/hip_runtime.h>
#include <cstdint>

#define HDIM 128
#define BN_EPS_F 1e-5f

// ============================ CSR build ============================
__global__ void hist_kernel(const int* __restrict__ dst, int E, int* __restrict__ cnt) {
  int i = blockIdx.x * blockDim.x + threadIdx.x;
  int stride = gridDim.x * blockDim.x;
  for (; i < E; i += stride) atomicAdd(&cnt[dst[i]], 1);
}

#define SCAN_T 256
#define SCAN_PER 8
#define SCAN_CHUNK (SCAN_T * SCAN_PER)

__global__ void scan_phase1(const int* __restrict__ cnt, int N, int* __restrict__ bsum) {
  __shared__ int sd[SCAN_T];
  int t = threadIdx.x;
  int base = blockIdx.x * SCAN_CHUNK + t * SCAN_PER;
  int s = 0;
#pragma unroll
  for (int k = 0; k < SCAN_PER; ++k) {
    int idx = base + k;
    if (idx < N) s += cnt[idx];
  }
  sd[t] = s;
  __syncthreads();
  for (int o = SCAN_T / 2; o > 0; o >>= 1) {
    if (t < o) sd[t] += sd[t + o];
    __syncthreads();
  }
  if (t == 0) bsum[blockIdx.x] = sd[0];
}

__global__ void scan_phase2(int* __restrict__ bsum, int NB, int* __restrict__ rowptr, int N) {
  if (threadIdx.x == 0 && blockIdx.x == 0) {
    int run = 0;
    for (int b = 0; b < NB; ++b) { int v = bsum[b]; bsum[b] = run; run += v; }
    rowptr[N] = run;
  }
}

__global__ void scan_phase3(const int* __restrict__ cnt, int N, const int* __restrict__ bsum,
                            int* __restrict__ rowptr, int* __restrict__ pos) {
  __shared__ int sd[SCAN_T];
  int t = threadIdx.x;
  int base = blockIdx.x * SCAN_CHUNK + t * SCAN_PER;
  int c[SCAN_PER];
  int s = 0;
#pragma unroll
  for (int k = 0; k < SCAN_PER; ++k) {
    int idx = base + k;
    c[k] = (idx < N) ? cnt[idx] : 0;
    s += c[k];
  }
  sd[t] = s;
  __syncthreads();
  int val = s;
  for (int o = 1; o < SCAN_T; o <<= 1) {
    int add = (t >= o) ? sd[t - o] : 0;
    __syncthreads();
    val += add;
    sd[t] = val;
    __syncthreads();
  }
  int off = bsum[blockIdx.x] + (val - s);  // exclusive prefix for this thread
#pragma unroll
  for (int k = 0; k < SCAN_PER; ++k) {
    int idx = base + k;
    if (idx < N) { rowptr[idx] = off; pos[idx] = off; off += c[k]; }
  }
}

__global__ void fill_kernel(const int* __restrict__ src, const int* __restrict__ dst, int E,
                            int* __restrict__ pos, int* __restrict__ col) {
  int i = blockIdx.x * blockDim.x + threadIdx.x;
  int stride = gridDim.x * blockDim.x;
  for (; i < E; i += stride) {
    int p = atomicAdd(&pos[dst[i]], 1);
    col[p] = src[i];
  }
}

// ============================ Aggregation ============================
// agg[i] = x[i] + sum_{e: dst==i} x[src[e]]  — one wave per node, float2/lane.
__global__ __launch_bounds__(256) void aggregate_kernel(const float* __restrict__ X,
    float* __restrict__ out, const int* __restrict__ rowptr, const int* __restrict__ col, int N) {
  int node = blockIdx.x * 4 + (threadIdx.x >> 6);
  if (node >= N) return;
  int lane = threadIdx.x & 63;
  const float2* Xv = (const float2*)X;
  size_t rb = (size_t)node * 64 + lane;
  float2 acc = Xv[rb];  // self term (GIN eps=0: x + agg)
  int s = rowptr[node], e = rowptr[node + 1];
  int i = s;
  for (; i + 4 <= e; i += 4) {
    int j0 = col[i], j1 = col[i + 1], j2 = col[i + 2], j3 = col[i + 3];
    float2 v0 = Xv[(size_t)j0 * 64 + lane];
    float2 v1 = Xv[(size_t)j1 * 64 + lane];
    float2 v2 = Xv[(size_t)j2 * 64 + lane];
    float2 v3 = Xv[(size_t)j3 * 64 + lane];
    acc.x += v0.x + v1.x + v2.x + v3.x;
    acc.y += v0.y + v1.y + v2.y + v3.y;
  }
  for (; i < e; ++i) {
    int j = col[i];
    float2 v = Xv[(size_t)j * 64 + lane];
    acc.x += v.x; acc.y += v.y;
  }
  ((float2*)out)[rb] = acc;
}

// ============================ Fused GIN MLP ============================
// In-place: A(N x 128) -> relu(A@W1+b1)@W2+b2, accumulating BN column sums/sumsq.
// NHALF=1: W1 128x128, W2 128x128 (res units). NHALF=2: W1 128x256, W2 256x128 (head),
// processed as two 128-wide halves sharing one 64KB LDS W buffer.
template <int NHALF>
__global__ __launch_bounds__(256, 1) void fused_mlp_kernel(
    float* __restrict__ A, const float* __restrict__ W1, const float* __restrict__ b1,
    const float* __restrict__ W2, const float* __restrict__ b2,
    float* __restrict__ stats, int N) {
  __shared__ float Xs[64][132];   // 33.8 KB (pad 132: +4 banks/row)
  __shared__ float Hs[64][132];   // 33.8 KB
  __shared__ float Ws[128][128];  // 64 KB, W1-half then W2-half
  const int tid = threadIdx.x;
  const int cg = tid & 15, rg = tid >> 4;
  const int c8 = cg * 8, rg4 = rg * 4;
  const int row0 = blockIdx.x * 64;

  // Load X tile (zeros for rows >= N)
#pragma unroll
  for (int it = 0; it < 8; ++it) {
    int l = tid + it * 256;
    int r = l >> 5, c4 = l & 31;
    float4 v = make_float4(0.f, 0.f, 0.f, 0.f);
    if (row0 + r < N) v = *(const float4*)&A[(size_t)(row0 + r) * HDIM + c4 * 4];
    *(float4*)&Xs[r][c4 * 4] = v;
  }

  float acc[4][8];
#pragma unroll
  for (int j = 0; j < 8; ++j) {
    float bv = b2[c8 + j];
#pragma unroll
    for (int i = 0; i < 4; ++i) acc[i][j] = bv;
  }

  for (int h = 0; h < NHALF; ++h) {
    __syncthreads();  // prior Ws/Hs readers done
    // W1 half -> Ws   (W1 row stride = NHALF*128)
#pragma unroll
    for (int it = 0; it < 16; ++it) {
      int l = tid + it * 256;
      int r = l >> 5, c4 = l & 31;
      *(float4*)&Ws[r][c4 * 4] =
          *(const float4*)&W1[(size_t)r * (NHALF * 128) + h * 128 + c4 * 4];
    }
    __syncthreads();

    float acc1[4][8];
#pragma unroll
    for (int j = 0; j < 8; ++j) {
      float bv = b1[h * 128 + c8 + j];
#pragma unroll
      for (int i = 0; i < 4; ++i) acc1[i][j] = bv;
    }
#pragma unroll 2
    for (int k = 0; k < 128; ++k) {
      float a0 = Xs[rg4 + 0][k], a1 = Xs[rg4 + 1][k];
      float a2 = Xs[rg4 + 2][k], a3 = Xs[rg4 + 3][k];
      float4 wA = *(const float4*)&Ws[k][c8];
      float4 wB = *(const float4*)&Ws[k][c8 + 4];
      float wv[8] = {wA.x, wA.y, wA.z, wA.w, wB.x, wB.y, wB.z, wB.w};
#pragma unroll
      for (int j = 0; j < 8; ++j) {
        acc1[0][j] = fmaf(a0, wv[j], acc1[0][j]);
        acc1[1][j] = fmaf(a1, wv[j], acc1[1][j]);
        acc1[2][j] = fmaf(a2, wv[j], acc1[2][j]);
        acc1[3][j] = fmaf(a3, wv[j], acc1[3][j]);
      }
    }
    // ReLU -> Hs
#pragma unroll
    for (int i = 0; i < 4; ++i) {
      float4 u, v;
      u.x = fmaxf(acc1[i][0], 0.f); u.y = fmaxf(acc1[i][1], 0.f);
      u.z = fmaxf(acc1[i][2], 0.f); u.w = fmaxf(acc1[i][3], 0.f);
      v.x = fmaxf(acc1[i][4], 0.f); v.y = fmaxf(acc1[i][5], 0.f);
      v.z = fmaxf(acc1[i][6], 0.f); v.w = fmaxf(acc1[i][7], 0.f);
      *(float4*)&Hs[rg4 + i][c8] = u;
      *(float4*)&Hs[rg4 + i][c8 + 4] = v;
    }
    __syncthreads();  // Hs ready; all W1-half reads done
    // W2 half -> Ws   (W2 row stride = 128)
#pragma unroll
    for (int it = 0; it < 16; ++it) {
      int l = tid + it * 256;
      int r = l >> 5, c4 = l & 31;
      *(float4*)&Ws[r][c4 * 4] = *(const float4*)&W2[(size_t)(h * 128 + r) * 128 + c4 * 4];
    }
    __syncthreads();
#pragma unroll 2
    for (int k = 0; k < 128; ++k) {
      float a0 = Hs[rg4 + 0][k], a1 = Hs[rg4 + 1][k];
      float a2 = Hs[rg4 + 2][k], a3 = Hs[rg4 + 3][k];
      float4 wA = *(const float4*)&Ws[k][c8];
      float4 wB = *(const float4*)&Ws[k][c8 + 4];
      float wv[8] = {wA.x, wA.y, wA.z, wA.w, wB.x, wB.y, wB.z, wB.w};
#pragma unroll
      for (int j = 0; j < 8; ++j) {
        acc[0][j] = fmaf(a0, wv[j], acc[0][j]);
        acc[1][j] = fmaf(a1, wv[j], acc[1][j]);
        acc[2][j] = fmaf(a2, wv[j], acc[2][j]);
        acc[3][j] = fmaf(a3, wv[j], acc[3][j]);
      }
    }
  }

  // Write out (in place) + BN partial sums
#pragma unroll
  for (int i = 0; i < 4; ++i) {
    int r = row0 + rg4 + i;
    if (r < N) {
      float4 u = make_float4(acc[i][0], acc[i][1], acc[i][2], acc[i][3]);
      float4 v = make_float4(acc[i][4], acc[i][5], acc[i][6], acc[i][7]);
      *(float4*)&A[(size_t)r * HDIM + c8] = u;
      *(float4*)&A[(size_t)r * HDIM + c8 + 4] = v;
    }
  }
  float* colsum = &Xs[0][0];           // [16][128] overlay (Xs no longer needed)
  float* colsq = &Xs[0][0] + 16 * 128;
#pragma unroll
  for (int j = 0; j < 8; ++j) {
    float s = 0.f, q = 0.f;
#pragma unroll
    for (int i = 0; i < 4; ++i) {
      if (row0 + rg4 + i < N) { s += acc[i][j]; q += acc[i][j] * acc[i][j]; }
    }
    colsum[rg * 128 + c8 + j] = s;
    colsq[rg * 128 + c8 + j] = q;
  }
  __syncthreads();
  if (tid < 128) {
    float S = 0.f, Q = 0.f;
#pragma unroll
    for (int r = 0; r < 16; ++r) { S += colsum[r * 128 + tid]; Q += colsq[r * 128 + tid]; }
    atomicAdd(&stats[tid], S);
    atomicAdd(&stats[128 + tid], Q);
  }
}

// ============================ BN finalize + apply ============================
__global__ void bn_finalize_kernel(float* __restrict__ stats, const float* __restrict__ g,
                                   const float* __restrict__ beta, float invN) {
  int c = threadIdx.x;
  if (c < HDIM) {
    float m = stats[c] * invN;
    float v = stats[128 + c] * invN - m * m;
    v = fmaxf(v, 0.f);
    float a = g[c] * rsqrtf(v + BN_EPS_F);
    stats[c] = a;
    stats[128 + c] = beta[c] - m * a;
  }
}

__global__ __launch_bounds__(256) void bn_relu_kernel(float* __restrict__ h,
    const float* __restrict__ stats, const float* __restrict__ identity, int nvec) {
  int i = blockIdx.x * blockDim.x + threadIdx.x;
  int stride = gridDim.x * blockDim.x;
  for (; i < nvec; i += stride) {
    int c4 = (i & 31) * 4;  // column of this float4 (row = 32 float4s)
    float4 x = ((const float4*)h)[i];
    float4 a = *(const float4*)&stats[c4];
    float4 b = *(const float4*)&stats[128 + c4];
    float4 o;
    o.x = fmaxf(fmaf(x.x, a.x, b.x), 0.f);
    o.y = fmaxf(fmaf(x.y, a.y, b.y), 0.f);
    o.z = fmaxf(fmaf(x.z, a.z, b.z), 0.f);
    o.w = fmaxf(fmaf(x.w, a.w, b.w), 0.f);
    if (identity) {
      float4 id = ((const float4*)identity)[i];
      o.x += id.x; o.y += id.y; o.z += id.z; o.w += id.w;
    }
    ((float4*)h)[i] = o;
  }
}

// ============================ Tail (GIN 128->32->3, no BN) ============================
__global__ __launch_bounds__(256, 1) void tail_kernel(
    const float* __restrict__ A, const float* __restrict__ W1, const float* __restrict__ b1,
    const float* __restrict__ W2, const float* __restrict__ b2, float* __restrict__ out, int N) {
  __shared__ float Xs[64][132];
  __shared__ float W1s[128][32];
  __shared__ float H1s[64][36];
  __shared__ float W2s[96];
  __shared__ float b1s[32];
  __shared__ float b2s[3];
  int tid = threadIdx.x;
  int row0 = blockIdx.x * 64;
#pragma unroll
  for (int it = 0; it < 8; ++it) {
    int l = tid + it * 256, r = l >> 5, c4 = l & 31;
    float4 v = make_float4(0.f, 0.f, 0.f, 0.f);
    if (row0 + r < N) v = *(const float4*)&A[(size_t)(row0 + r) * HDIM + c4 * 4];
    *(float4*)&Xs[r][c4 * 4] = v;
  }
#pragma unroll
  for (int it = 0; it < 4; ++it) {
    int l = tid + it * 256;  // 1024 float4s = 128 rows x 8
    int r = l >> 3, c4 = l & 7;
    *(float4*)&W1s[r][c4 * 4] = *(const float4*)&W1[r * 32 + c4 * 4];
  }
  if (tid < 96) W2s[tid] = W2[tid];
  if (tid < 32) b1s[tid] = b1[tid];
  if (tid < 3) b2s[tid] = b2[tid];
  __syncthreads();
  {
    int r = tid >> 2;
    int c0 = (tid & 3) * 8;
    float acc1[8];
#pragma unroll
    for (int j = 0; j < 8; ++j) acc1[j] = b1s[c0 + j];
#pragma unroll 2
    for (int k = 0; k < 128; ++k) {
      float xv = Xs[r][k];
      float4 wA = *(const float4*)&W1s[k][c0];
      float4 wB = *(const float4*)&W1s[k][c0 + 4];
      acc1[0] = fmaf(xv, wA.x, acc1[0]);
      acc1[1] = fmaf(xv, wA.y, acc1[1]);
      acc1[2] = fmaf(xv, wA.z, acc1[2]);
      acc1[3] = fmaf(xv, wA.w, acc1[3]);
      acc1[4] = fmaf(xv, wB.x, acc1[4]);
      acc1[5] = fmaf(xv, wB.y, acc1[5]);
      acc1[6] = fmaf(xv, wB.z, acc1[6]);
      acc1[7] = fmaf(xv, wB.w, acc1[7]);
    }
#pragma unroll
    for (int j = 0; j < 8; ++j) H1s[r][c0 + j] = fmaxf(acc1[j], 0.f);
  }
  __syncthreads();
  if (tid < 192) {
    int r = tid / 3, c = tid - (tid / 3) * 3;
    float accv = b2s[c];
#pragma unroll
    for (int k = 0; k < 32; ++k) accv = fmaf(H1s[r][k], W2s[k * 3 + c], accv);
    if (row0 + r < N) out[(size_t)(row0 + r) * 3 + c] = accv;
  }
}

// ============================ Host launcher ============================
extern "C" void kernel_launch(void* const* d_in, const int* in_sizes, int n_in,
                              void* d_out, int out_size, void* d_ws, size_t ws_size,
                              hipStream_t stream) {
  const float* x = (const float*)d_in[0];
  const int* ei = (const int*)d_in[1];
  const float* head_w1 = (const float*)d_in[2];
  const float* head_b1 = (const float*)d_in[3];
  const float* head_w2 = (const float*)d_in[4];
  const float* head_b2 = (const float*)d_in[5];
  const float* head_g = (const float*)d_in[6];
  const float* head_bt = (const float*)d_in[7];
  const float* res_w1 = (const float*)d_in[8];
  const float* res_b1 = (const float*)d_in[9];
  const float* res_w2 = (const float*)d_in[10];
  const float* res_b2 = (const float*)d_in[11];
  const float* res_g = (const float*)d_in[12];
  const float* res_bt = (const float*)d_in[13];
  const float* tail_w1 = (const float*)d_in[14];
  const float* tail_b1 = (const float*)d_in[15];
  const float* tail_w2 = (const float*)d_in[16];
  const float* tail_b2 = (const float*)d_in[17];

  const int N = in_sizes[0] / HDIM;
  const int E = in_sizes[1] / 2;
  const int* srcp = ei;
  const int* dstp = ei + E;

  char* base = (char*)d_ws;
  size_t off = 0;
  auto alloc = [&](size_t bytes) -> void* {
    void* p = base + off;
    off += (bytes + 255) & ~(size_t)255;
    return p;
  };
  float* p0 = (float*)alloc((size_t)N * HDIM * 4);
  float* p1 = (float*)alloc((size_t)N * HDIM * 4);
  float* p2 = (float*)alloc((size_t)N * HDIM * 4);
  int* cnt = (int*)alloc((size_t)N * 4);
  int* pos = (int*)alloc((size_t)N * 4);
  int* rowptr = (int*)alloc((size_t)(N + 1) * 4);
  int* colb = (int*)alloc((size_t)E * 4);
  const int NB = (N + SCAN_CHUNK - 1) / SCAN_CHUNK;
  int* bsum = (int*)alloc((size_t)NB * 4);
  float* stats = (float*)alloc(256 * 4);
  (void)ws_size; (void)n_in; (void)out_size;

  // ---- CSR build (edge structure shared by all 8 layers) ----
  hipMemsetAsync(cnt, 0, (size_t)N * 4, stream);
  hist_kernel<<<2048, 256, 0, stream>>>(dstp, E, cnt);
  scan_phase1<<<NB, SCAN_T, 0, stream>>>(cnt, N, bsum);
  scan_phase2<<<1, 64, 0, stream>>>(bsum, NB, rowptr, N);
  scan_phase3<<<NB, SCAN_T, 0, stream>>>(cnt, N, bsum, rowptr, pos);
  fill_kernel<<<2048, 256, 0, stream>>>(srcp, dstp, E, pos, colb);

  const int aggGrid = (N + 3) / 4;
  const int mlpGrid = (N + 63) / 64;
  const float invN = 1.0f / (float)N;

  // ---- head: GIN(128->256->128) + BN + ReLU ----
  aggregate_kernel<<<aggGrid, 256, 0, stream>>>(x, p0, rowptr, colb, N);
  hipMemsetAsync(stats, 0, 256 * 4, stream);
  fused_mlp_kernel<2><<<mlpGrid, 256, 0, stream>>>(p0, head_w1, head_b1, head_w2, head_b2, stats, N);
  bn_finalize_kernel<<<1, 128, 0, stream>>>(stats, head_g, head_bt, invN);
  bn_relu_kernel<<<2048, 256, 0, stream>>>(p0, stats, (const float*)nullptr, N * (HDIM / 4));

  // ---- residual blocks ----
  auto res_unit = [&](float* bin, float* bout, int u, const float* ident) {
    aggregate_kernel<<<aggGrid, 256, 0, stream>>>(bin, bout, rowptr, colb, N);
    hipMemsetAsync(stats, 0, 256 * 4, stream);
    fused_mlp_kernel<1><<<mlpGrid, 256, 0, stream>>>(
        bout, res_w1 + (size_t)u * HDIM * HDIM, res_b1 + (size_t)u * HDIM,
        res_w2 + (size_t)u * HDIM * HDIM, res_b2 + (size_t)u * HDIM, stats, N);
    bn_finalize_kernel<<<1, 128, 0, stream>>>(stats, res_g + (size_t)u * HDIM,
                                              res_bt + (size_t)u * HDIM, invN);
    bn_relu_kernel<<<2048, 256, 0, stream>>>(bout, stats, ident, N * (HDIM / 4));
  };
  // 3-buffer rotation keeps the residual identity alive without copies.
  res_unit(p0, p1, 0, nullptr);
  res_unit(p1, p2, 1, p0);
  res_unit(p2, p0, 2, nullptr);
  res_unit(p0, p1, 3, p2);
  res_unit(p1, p2, 4, nullptr);
  res_unit(p2, p0, 5, p1);

  // ---- tail: GIN(128->32->3), no BN ----
  aggregate_kernel<<<aggGrid, 256, 0, stream>>>(p0, p1, rowptr, colb, N);
  tail_kernel<<<mlpGrid, 256, 0, stream>>>(p1, tail_w1, tail_b1, tail_w2, tail_b2,
                                           (float*)d_out, N);
}

// Round 2
// 2261.429 us; speedup vs baseline: 1.2315x; 1.2315x over previous
//
#include <hip/hip_runtime.h>
#include <cstdint>

#define HDIM 128
#define BN_EPS_F 1e-5f

// ============================ CSR build ============================
__global__ void hist_kernel(const int* __restrict__ dst, int E, int* __restrict__ cnt) {
  int i = blockIdx.x * blockDim.x + threadIdx.x;
  int stride = gridDim.x * blockDim.x;
  for (; i < E; i += stride) atomicAdd(&cnt[dst[i]], 1);
}

#define SCAN_T 256
#define SCAN_PER 8
#define SCAN_CHUNK (SCAN_T * SCAN_PER)

__global__ void scan_phase1(const int* __restrict__ cnt, int N, int* __restrict__ bsum) {
  __shared__ int sd[SCAN_T];
  int t = threadIdx.x;
  int base = blockIdx.x * SCAN_CHUNK + t * SCAN_PER;
  int s = 0;
#pragma unroll
  for (int k = 0; k < SCAN_PER; ++k) {
    int idx = base + k;
    if (idx < N) s += cnt[idx];
  }
  sd[t] = s;
  __syncthreads();
  for (int o = SCAN_T / 2; o > 0; o >>= 1) {
    if (t < o) sd[t] += sd[t + o];
    __syncthreads();
  }
  if (t == 0) bsum[blockIdx.x] = sd[0];
}

__global__ void scan_phase2(int* __restrict__ bsum, int NB, int* __restrict__ rowptr, int N) {
  if (threadIdx.x == 0 && blockIdx.x == 0) {
    int run = 0;
    for (int b = 0; b < NB; ++b) { int v = bsum[b]; bsum[b] = run; run += v; }
    rowptr[N] = run;
  }
}

__global__ void scan_phase3(const int* __restrict__ cnt, int N, const int* __restrict__ bsum,
                            int* __restrict__ rowptr, int* __restrict__ pos) {
  __shared__ int sd[SCAN_T];
  int t = threadIdx.x;
  int base = blockIdx.x * SCAN_CHUNK + t * SCAN_PER;
  int c[SCAN_PER];
  int s = 0;
#pragma unroll
  for (int k = 0; k < SCAN_PER; ++k) {
    int idx = base + k;
    c[k] = (idx < N) ? cnt[idx] : 0;
    s += c[k];
  }
  sd[t] = s;
  __syncthreads();
  int val = s;
  for (int o = 1; o < SCAN_T; o <<= 1) {
    int add = (t >= o) ? sd[t - o] : 0;
    __syncthreads();
    val += add;
    sd[t] = val;
    __syncthreads();
  }
  int off = bsum[blockIdx.x] + (val - s);  // exclusive prefix for this thread
#pragma unroll
  for (int k = 0; k < SCAN_PER; ++k) {
    int idx = base + k;
    if (idx < N) { rowptr[idx] = off; pos[idx] = off; off += c[k]; }
  }
}

__global__ void fill_kernel(const int* __restrict__ src, const int* __restrict__ dst, int E,
                            int* __restrict__ pos, int* __restrict__ col) {
  int i = blockIdx.x * blockDim.x + threadIdx.x;
  int stride = gridDim.x * blockDim.x;
  for (; i < E; i += stride) {
    int p = atomicAdd(&pos[dst[i]], 1);
    col[p] = src[i];
  }
}

// ============================ Aggregation ============================
// agg[i] = x[i] + sum_{e: dst==i} x[src[e]]  — one wave per node, float2/lane.
__global__ __launch_bounds__(256) void aggregate_kernel(const float* __restrict__ X,
    float* __restrict__ out, const int* __restrict__ rowptr, const int* __restrict__ col, int N) {
  int node = blockIdx.x * 4 + (threadIdx.x >> 6);
  if (node >= N) return;
  int lane = threadIdx.x & 63;
  const float2* Xv = (const float2*)X;
  size_t rb = (size_t)node * 64 + lane;
  float2 acc = Xv[rb];  // self term (GIN eps=0: x + agg)
  int s = rowptr[node], e = rowptr[node + 1];
  int i = s;
  for (; i + 4 <= e; i += 4) {
    int j0 = col[i], j1 = col[i + 1], j2 = col[i + 2], j3 = col[i + 3];
    float2 v0 = Xv[(size_t)j0 * 64 + lane];
    float2 v1 = Xv[(size_t)j1 * 64 + lane];
    float2 v2 = Xv[(size_t)j2 * 64 + lane];
    float2 v3 = Xv[(size_t)j3 * 64 + lane];
    acc.x += v0.x + v1.x + v2.x + v3.x;
    acc.y += v0.y + v1.y + v2.y + v3.y;
  }
  for (; i < e; ++i) {
    int j = col[i];
    float2 v = Xv[(size_t)j * 64 + lane];
    acc.x += v.x; acc.y += v.y;
  }
  ((float2*)out)[rb] = acc;
}

// ============================ Fused GIN MLP ============================
// Thread layout: 256 threads; cg = tid&15 owns output cols {4cg..4cg+3} U {64+4cg..+3}
// (split halves -> W-read bank quads = cg&7, 2-way = free). rg = tid>>4 owns RPT rows.
// W staged in 32-row k-chunks (16 KB) -> LDS/block ~50 KB -> 3 blocks/CU.

__device__ __forceinline__ void stage_w(float (*Ws)[128], const float* __restrict__ src,
                                        int ldw) {
  int tid = threadIdx.x;
#pragma unroll
  for (int it = 0; it < 4; ++it) {
    int l = tid + it * 256;
    int r = l >> 5, c4 = l & 31;
    *(float4*)&Ws[r][c4 * 4] = *(const float4*)&src[(size_t)r * ldw + c4 * 4];
  }
}

template <int RPT>
__device__ __forceinline__ void gemm_chunk(const float (*B)[132], int k0,
    const float (*Wc)[128], int rg, int cg, float (&acc)[RPT][8]) {
#pragma unroll
  for (int kq = 0; kq < 8; ++kq) {  // 8 quads of k within the 32-row chunk
    float4 a4[RPT];
#pragma unroll
    for (int i = 0; i < RPT; ++i)
      a4[i] = *(const float4*)&B[rg * RPT + i][k0 + kq * 4];
#pragma unroll
    for (int t = 0; t < 4; ++t) {
      int kk = kq * 4 + t;
      float4 wl = *(const float4*)&Wc[kk][cg * 4];
      float4 wh = *(const float4*)&Wc[kk][64 + cg * 4];
      float wv[8] = {wl.x, wl.y, wl.z, wl.w, wh.x, wh.y, wh.z, wh.w};
#pragma unroll
      for (int i = 0; i < RPT; ++i) {
        const float* ap = reinterpret_cast<const float*>(&a4[i]);
        float av = ap[t];
#pragma unroll
        for (int j = 0; j < 8; ++j) acc[i][j] = fmaf(av, wv[j], acc[i][j]);
      }
    }
  }
}

// In-place: A(N x 128) -> relu(A@W1+b1)@W2+b2, accumulating BN column sums/sumsq.
// NHALF=1 (res): ROWS=64, H overwrites the X tile.
// NHALF=2 (head, W1 128x256): ROWS=32, separate H buffer, two column-halves.
template <int ROWS, int NHALF>
__global__ __launch_bounds__(256, 3) void fused_mlp_kernel(
    float* __restrict__ A, const float* __restrict__ W1, const float* __restrict__ b1,
    const float* __restrict__ W2, const float* __restrict__ b2,
    float* __restrict__ stats, int N) {
  constexpr int RPT = ROWS / 16;
  __shared__ float Xs[ROWS][132];
  __shared__ float Ws[32][128];
  __shared__ float Hs[(NHALF == 2 ? ROWS : 1)][132];
  const int tid = threadIdx.x;
  const int cg = tid & 15, rg = tid >> 4;
  const int c4lo = cg * 4, c4hi = 64 + cg * 4;
  const int row0 = blockIdx.x * ROWS;

  // Load X tile (zeros for rows >= N)
#pragma unroll
  for (int it = 0; it < ROWS / 8; ++it) {
    int l = tid + it * 256;
    int r = l >> 5, c4 = l & 31;
    float4 v = make_float4(0.f, 0.f, 0.f, 0.f);
    if (row0 + r < N) v = *(const float4*)&A[(size_t)(row0 + r) * HDIM + c4 * 4];
    *(float4*)&Xs[r][c4 * 4] = v;
  }

  float (*Hb)[132];
  if constexpr (NHALF == 2) Hb = Hs; else Hb = Xs;

  float acc[RPT][8];
#pragma unroll
  for (int j = 0; j < 4; ++j) {
    float bl = b2[c4lo + j], bh = b2[c4hi + j];
#pragma unroll
    for (int i = 0; i < RPT; ++i) { acc[i][j] = bl; acc[i][4 + j] = bh; }
  }

  for (int h = 0; h < NHALF; ++h) {
    float acc1[RPT][8];
#pragma unroll
    for (int j = 0; j < 4; ++j) {
      float bl = b1[h * 128 + c4lo + j], bh = b1[h * 128 + c4hi + j];
#pragma unroll
      for (int i = 0; i < RPT; ++i) { acc1[i][j] = bl; acc1[i][4 + j] = bh; }
    }
    // GEMM1: X @ W1[:, h*128 : h*128+128]
    for (int c = 0; c < 4; ++c) {
      __syncthreads();
      stage_w(Ws, W1 + (size_t)(c * 32) * (NHALF * 128) + h * 128, NHALF * 128);
      __syncthreads();
      gemm_chunk<RPT>(Xs, c * 32, Ws, rg, cg, acc1);
    }
    __syncthreads();  // all GEMM1 reads of Xs/Ws done
    // ReLU -> H
#pragma unroll
    for (int i = 0; i < RPT; ++i) {
      float4 u, v;
      u.x = fmaxf(acc1[i][0], 0.f); u.y = fmaxf(acc1[i][1], 0.f);
      u.z = fmaxf(acc1[i][2], 0.f); u.w = fmaxf(acc1[i][3], 0.f);
      v.x = fmaxf(acc1[i][4], 0.f); v.y = fmaxf(acc1[i][5], 0.f);
      v.z = fmaxf(acc1[i][6], 0.f); v.w = fmaxf(acc1[i][7], 0.f);
      *(float4*)&Hb[rg * RPT + i][c4lo] = u;
      *(float4*)&Hb[rg * RPT + i][c4hi] = v;
    }
    // GEMM2: H @ W2[h*128 : h*128+128, :]
    stage_w(Ws, W2 + (size_t)(h * 128) * 128, 128);
    __syncthreads();  // H + first W2 chunk ready
    gemm_chunk<RPT>(Hb, 0, Ws, rg, cg, acc);
    for (int c = 1; c < 4; ++c) {
      __syncthreads();
      stage_w(Ws, W2 + (size_t)(h * 128 + c * 32) * 128, 128);
      __syncthreads();
      gemm_chunk<RPT>(Hb, c * 32, Ws, rg, cg, acc);
    }
  }

  // Write out (in place) + BN partial sums
#pragma unroll
  for (int i = 0; i < RPT; ++i) {
    int r = row0 + rg * RPT + i;
    if (r < N) {
      float4 u = make_float4(acc[i][0], acc[i][1], acc[i][2], acc[i][3]);
      float4 v = make_float4(acc[i][4], acc[i][5], acc[i][6], acc[i][7]);
      *(float4*)&A[(size_t)r * HDIM + c4lo] = u;
      *(float4*)&A[(size_t)r * HDIM + c4hi] = v;
    }
  }
  __syncthreads();  // all LDS compute reads done; overlay Xs with stat partials
  float* colsum = &Xs[0][0];            // [16][128]
  float* colsq = &Xs[0][0] + 16 * 128;  // [16][128]
#pragma unroll
  for (int j = 0; j < 8; ++j) {
    int colj = (j < 4) ? (c4lo + j) : (c4hi + j - 4);
    float s = 0.f, q = 0.f;
#pragma unroll
    for (int i = 0; i < RPT; ++i) {
      if (row0 + rg * RPT + i < N) { s += acc[i][j]; q += acc[i][j] * acc[i][j]; }
    }
    colsum[rg * 128 + colj] = s;
    colsq[rg * 128 + colj] = q;
  }
  __syncthreads();
  if (tid < 128) {
    float S = 0.f, Q = 0.f;
#pragma unroll
    for (int r = 0; r < 16; ++r) { S += colsum[r * 128 + tid]; Q += colsq[r * 128 + tid]; }
    atomicAdd(&stats[tid], S);
    atomicAdd(&stats[128 + tid], Q);
  }
}

// ============================ BN finalize + apply ============================
__global__ void bn_finalize_kernel(float* __restrict__ stats, const float* __restrict__ g,
                                   const float* __restrict__ beta, float invN) {
  int c = threadIdx.x;
  if (c < HDIM) {
    float m = stats[c] * invN;
    float v = stats[128 + c] * invN - m * m;
    v = fmaxf(v, 0.f);
    float a = g[c] * rsqrtf(v + BN_EPS_F);
    stats[c] = a;
    stats[128 + c] = beta[c] - m * a;
  }
}

__global__ __launch_bounds__(256) void bn_relu_kernel(float* __restrict__ h,
    const float* __restrict__ stats, const float* __restrict__ identity, int nvec) {
  int i = blockIdx.x * blockDim.x + threadIdx.x;
  int stride = gridDim.x * blockDim.x;
  for (; i < nvec; i += stride) {
    int c4 = (i & 31) * 4;  // column of this float4 (row = 32 float4s)
    float4 x = ((const float4*)h)[i];
    float4 a = *(const float4*)&stats[c4];
    float4 b = *(const float4*)&stats[128 + c4];
    float4 o;
    o.x = fmaxf(fmaf(x.x, a.x, b.x), 0.f);
    o.y = fmaxf(fmaf(x.y, a.y, b.y), 0.f);
    o.z = fmaxf(fmaf(x.z, a.z, b.z), 0.f);
    o.w = fmaxf(fmaf(x.w, a.w, b.w), 0.f);
    if (identity) {
      float4 id = ((const float4*)identity)[i];
      o.x += id.x; o.y += id.y; o.z += id.z; o.w += id.w;
    }
    ((float4*)h)[i] = o;
  }
}

// ============================ Tail (GIN 128->32->3, no BN) ============================
__global__ __launch_bounds__(256, 1) void tail_kernel(
    const float* __restrict__ A, const float* __restrict__ W1, const float* __restrict__ b1,
    const float* __restrict__ W2, const float* __restrict__ b2, float* __restrict__ out, int N) {
  __shared__ float Xs[64][132];
  __shared__ float W1s[128][32];
  __shared__ float H1s[64][36];
  __shared__ float W2s[96];
  __shared__ float b1s[32];
  __shared__ float b2s[3];
  int tid = threadIdx.x;
  int row0 = blockIdx.x * 64;
#pragma unroll
  for (int it = 0; it < 8; ++it) {
    int l = tid + it * 256, r = l >> 5, c4 = l & 31;
    float4 v = make_float4(0.f, 0.f, 0.f, 0.f);
    if (row0 + r < N) v = *(const float4*)&A[(size_t)(row0 + r) * HDIM + c4 * 4];
    *(float4*)&Xs[r][c4 * 4] = v;
  }
#pragma unroll
  for (int it = 0; it < 4; ++it) {
    int l = tid + it * 256;  // 1024 float4s = 128 rows x 8
    int r = l >> 3, c4 = l & 7;
    *(float4*)&W1s[r][c4 * 4] = *(const float4*)&W1[r * 32 + c4 * 4];
  }
  if (tid < 96) W2s[tid] = W2[tid];
  if (tid < 32) b1s[tid] = b1[tid];
  if (tid < 3) b2s[tid] = b2[tid];
  __syncthreads();
  {
    int r = tid >> 2;
    int c0 = (tid & 3) * 8;
    float acc1[8];
#pragma unroll
    for (int j = 0; j < 8; ++j) acc1[j] = b1s[c0 + j];
#pragma unroll 2
    for (int k = 0; k < 128; ++k) {
      float xv = Xs[r][k];
      float4 wA = *(const float4*)&W1s[k][c0];
      float4 wB = *(const float4*)&W1s[k][c0 + 4];
      acc1[0] = fmaf(xv, wA.x, acc1[0]);
      acc1[1] = fmaf(xv, wA.y, acc1[1]);
      acc1[2] = fmaf(xv, wA.z, acc1[2]);
      acc1[3] = fmaf(xv, wA.w, acc1[3]);
      acc1[4] = fmaf(xv, wB.x, acc1[4]);
      acc1[5] = fmaf(xv, wB.y, acc1[5]);
      acc1[6] = fmaf(xv, wB.z, acc1[6]);
      acc1[7] = fmaf(xv, wB.w, acc1[7]);
    }
#pragma unroll
    for (int j = 0; j < 8; ++j) H1s[r][c0 + j] = fmaxf(acc1[j], 0.f);
  }
  __syncthreads();
  if (tid < 192) {
    int r = tid / 3, c = tid - (tid / 3) * 3;
    float accv = b2s[c];
#pragma unroll
    for (int k = 0; k < 32; ++k) accv = fmaf(H1s[r][k], W2s[k * 3 + c], accv);
    if (row0 + r < N) out[(size_t)(row0 + r) * 3 + c] = accv;
  }
}

// ============================ Host launcher ============================
extern "C" void kernel_launch(void* const* d_in, const int* in_sizes, int n_in,
                              void* d_out, int out_size, void* d_ws, size_t ws_size,
                              hipStream_t stream) {
  const float* x = (const float*)d_in[0];
  const int* ei = (const int*)d_in[1];
  const float* head_w1 = (const float*)d_in[2];
  const float* head_b1 = (const float*)d_in[3];
  const float* head_w2 = (const float*)d_in[4];
  const float* head_b2 = (const float*)d_in[5];
  const float* head_g = (const float*)d_in[6];
  const float* head_bt = (const float*)d_in[7];
  const float* res_w1 = (const float*)d_in[8];
  const float* res_b1 = (const float*)d_in[9];
  const float* res_w2 = (const float*)d_in[10];
  const float* res_b2 = (const float*)d_in[11];
  const float* res_g = (const float*)d_in[12];
  const float* res_bt = (const float*)d_in[13];
  const float* tail_w1 = (const float*)d_in[14];
  const float* tail_b1 = (const float*)d_in[15];
  const float* tail_w2 = (const float*)d_in[16];
  const float* tail_b2 = (const float*)d_in[17];

  const int N = in_sizes[0] / HDIM;
  const int E = in_sizes[1] / 2;
  const int* srcp = ei;
  const int* dstp = ei + E;

  char* base = (char*)d_ws;
  size_t off = 0;
  auto alloc = [&](size_t bytes) -> void* {
    void* p = base + off;
    off += (bytes + 255) & ~(size_t)255;
    return p;
  };
  float* p0 = (float*)alloc((size_t)N * HDIM * 4);
  float* p1 = (float*)alloc((size_t)N * HDIM * 4);
  float* p2 = (float*)alloc((size_t)N * HDIM * 4);
  int* cnt = (int*)alloc((size_t)N * 4);
  int* pos = (int*)alloc((size_t)N * 4);
  int* rowptr = (int*)alloc((size_t)(N + 1) * 4);
  int* colb = (int*)alloc((size_t)E * 4);
  const int NB = (N + SCAN_CHUNK - 1) / SCAN_CHUNK;
  int* bsum = (int*)alloc((size_t)NB * 4);
  float* stats = (float*)alloc(256 * 4);
  (void)ws_size; (void)n_in; (void)out_size;

  // ---- CSR build (edge structure shared by all 8 layers) ----
  hipMemsetAsync(cnt, 0, (size_t)N * 4, stream);
  hist_kernel<<<2048, 256, 0, stream>>>(dstp, E, cnt);
  scan_phase1<<<NB, SCAN_T, 0, stream>>>(cnt, N, bsum);
  scan_phase2<<<1, 64, 0, stream>>>(bsum, NB, rowptr, N);
  scan_phase3<<<NB, SCAN_T, 0, stream>>>(cnt, N, bsum, rowptr, pos);
  fill_kernel<<<2048, 256, 0, stream>>>(srcp, dstp, E, pos, colb);

  const int aggGrid = (N + 3) / 4;
  const float invN = 1.0f / (float)N;

  // ---- head: GIN(128->256->128) + BN + ReLU ----
  aggregate_kernel<<<aggGrid, 256, 0, stream>>>(x, p0, rowptr, colb, N);
  hipMemsetAsync(stats, 0, 256 * 4, stream);
  fused_mlp_kernel<32, 2><<<(N + 31) / 32, 256, 0, stream>>>(p0, head_w1, head_b1, head_w2,
                                                             head_b2, stats, N);
  bn_finalize_kernel<<<1, 128, 0, stream>>>(stats, head_g, head_bt, invN);
  bn_relu_kernel<<<2048, 256, 0, stream>>>(p0, stats, (const float*)nullptr, N * (HDIM / 4));

  // ---- residual blocks ----
  auto res_unit = [&](float* bin, float* bout, int u, const float* ident) {
    aggregate_kernel<<<aggGrid, 256, 0, stream>>>(bin, bout, rowptr, colb, N);
    hipMemsetAsync(stats, 0, 256 * 4, stream);
    fused_mlp_kernel<64, 1><<<(N + 63) / 64, 256, 0, stream>>>(
        bout, res_w1 + (size_t)u * HDIM * HDIM, res_b1 + (size_t)u * HDIM,
        res_w2 + (size_t)u * HDIM * HDIM, res_b2 + (size_t)u * HDIM, stats, N);
    bn_finalize_kernel<<<1, 128, 0, stream>>>(stats, res_g + (size_t)u * HDIM,
                                              res_bt + (size_t)u * HDIM, invN);
    bn_relu_kernel<<<2048, 256, 0, stream>>>(bout, stats, ident, N * (HDIM / 4));
  };
  // 3-buffer rotation keeps the residual identity alive without copies.
  res_unit(p0, p1, 0, nullptr);
  res_unit(p1, p2, 1, p0);
  res_unit(p2, p0, 2, nullptr);
  res_unit(p0, p1, 3, p2);
  res_unit(p1, p2, 4, nullptr);
  res_unit(p2, p0, 5, p1);

  // ---- tail: GIN(128->32->3), no BN ----
  aggregate_kernel<<<aggGrid, 256, 0, stream>>>(p0, p1, rowptr, colb, N);
  tail_kernel<<<(N + 63) / 64, 256, 0, stream>>>(p1, tail_w1, tail_b1, tail_w2, tail_b2,
                                                 (float*)d_out, N);
}

// Round 3
// 1996.253 us; speedup vs baseline: 1.3951x; 1.1328x over previous
//
#include <hip/hip_runtime.h>
#include <cstdint>

#define HDIM 128
#define BN_EPS_F 1e-5f

typedef _Float16 half8 __attribute__((ext_vector_type(8)));
typedef _Float16 half4v __attribute__((ext_vector_type(4)));
typedef float f32x4 __attribute__((ext_vector_type(4)));

#define PA 136  // f16 pitch of A/H tiles (136*2B = 272 B rows, 16B aligned, 2-way banks)
#define PW 72   // f16 pitch of W slabs (144 B rows, 16B aligned, 2-way banks)

// ============================ CSR build ============================
__global__ void hist_kernel(const int* __restrict__ dst, int E, int* __restrict__ cnt) {
  int i = blockIdx.x * blockDim.x + threadIdx.x;
  int stride = gridDim.x * blockDim.x;
  for (; i < E; i += stride) atomicAdd(&cnt[dst[i]], 1);
}

#define SCAN_T 256
#define SCAN_PER 8
#define SCAN_CHUNK (SCAN_T * SCAN_PER)

__global__ void scan_phase1(const int* __restrict__ cnt, int N, int* __restrict__ bsum) {
  __shared__ int sd[SCAN_T];
  int t = threadIdx.x;
  int base = blockIdx.x * SCAN_CHUNK + t * SCAN_PER;
  int s = 0;
#pragma unroll
  for (int k = 0; k < SCAN_PER; ++k) {
    int idx = base + k;
    if (idx < N) s += cnt[idx];
  }
  sd[t] = s;
  __syncthreads();
  for (int o = SCAN_T / 2; o > 0; o >>= 1) {
    if (t < o) sd[t] += sd[t + o];
    __syncthreads();
  }
  if (t == 0) bsum[blockIdx.x] = sd[0];
}

__global__ void scan_phase2(int* __restrict__ bsum, int NB, int* __restrict__ rowptr, int N) {
  if (threadIdx.x == 0 && blockIdx.x == 0) {
    int run = 0;
    for (int b = 0; b < NB; ++b) { int v = bsum[b]; bsum[b] = run; run += v; }
    rowptr[N] = run;
  }
}

__global__ void scan_phase3(const int* __restrict__ cnt, int N, const int* __restrict__ bsum,
                            int* __restrict__ rowptr, int* __restrict__ pos) {
  __shared__ int sd[SCAN_T];
  int t = threadIdx.x;
  int base = blockIdx.x * SCAN_CHUNK + t * SCAN_PER;
  int c[SCAN_PER];
  int s = 0;
#pragma unroll
  for (int k = 0; k < SCAN_PER; ++k) {
    int idx = base + k;
    c[k] = (idx < N) ? cnt[idx] : 0;
    s += c[k];
  }
  sd[t] = s;
  __syncthreads();
  int val = s;
  for (int o = 1; o < SCAN_T; o <<= 1) {
    int add = (t >= o) ? sd[t - o] : 0;
    __syncthreads();
    val += add;
    sd[t] = val;
    __syncthreads();
  }
  int off = bsum[blockIdx.x] + (val - s);
#pragma unroll
  for (int k = 0; k < SCAN_PER; ++k) {
    int idx = base + k;
    if (idx < N) { rowptr[idx] = off; pos[idx] = off; off += c[k]; }
  }
}

__global__ void fill_kernel(const int* __restrict__ src, const int* __restrict__ dst, int E,
                            int* __restrict__ pos, int* __restrict__ col) {
  int i = blockIdx.x * blockDim.x + threadIdx.x;
  int stride = gridDim.x * blockDim.x;
  for (; i < E; i += stride) {
    int p = atomicAdd(&pos[dst[i]], 1);
    col[p] = src[i];
  }
}

// ============================ Aggregation ============================
__global__ __launch_bounds__(256) void aggregate_kernel(const float* __restrict__ X,
    float* __restrict__ out, const int* __restrict__ rowptr, const int* __restrict__ col, int N) {
  int node = blockIdx.x * 4 + (threadIdx.x >> 6);
  if (node >= N) return;
  int lane = threadIdx.x & 63;
  const float2* Xv = (const float2*)X;
  size_t rb = (size_t)node * 64 + lane;
  float2 acc = Xv[rb];  // self term (GIN eps=0)
  int s = rowptr[node], e = rowptr[node + 1];
  int i = s;
  for (; i + 4 <= e; i += 4) {
    int j0 = col[i], j1 = col[i + 1], j2 = col[i + 2], j3 = col[i + 3];
    float2 v0 = Xv[(size_t)j0 * 64 + lane];
    float2 v1 = Xv[(size_t)j1 * 64 + lane];
    float2 v2 = Xv[(size_t)j2 * 64 + lane];
    float2 v3 = Xv[(size_t)j3 * 64 + lane];
    acc.x += v0.x + v1.x + v2.x + v3.x;
    acc.y += v0.y + v1.y + v2.y + v3.y;
  }
  for (; i < e; ++i) {
    int j = col[i];
    float2 v = Xv[(size_t)j * 64 + lane];
    acc.x += v.x; acc.y += v.y;
  }
  ((float2*)out)[rb] = acc;
}

// ============================ Weight prep: transpose + f16 hi/lo split ============
// W[k][n] (row-major, K x Nn) -> hi/lo[n][k]
__global__ void wprep_kernel(const float* __restrict__ W, _Float16* __restrict__ hi,
                             _Float16* __restrict__ lo, int K, int Nn) {
  int idx = blockIdx.x * 256 + threadIdx.x;
  if (idx >= K * Nn) return;
  int n = idx / K, k = idx - n * K;
  float v = W[(size_t)k * Nn + n];
  _Float16 h = (_Float16)v;
  hi[idx] = h;
  lo[idx] = (_Float16)(v - (float)h);
}

// ============================ MFMA fused GIN MLP (f16x3 split) ============================
// A(N x 128) -> relu(A@W1+b1)@W2+b2 in place, + BN column sums/sumsq.
// MF=2/NH=1 (res, BM=64, H aliases A); MF=1/NH=2 (head, BM=32, separate H).
// 4 waves: wr=wave>>1 row-stripe, wc=wave&1 col-half. Wave tile: (MF*16) x 64.
// Each product split: hi*hi + lo*hi + hi*lo (fp32 accum) ~ fp32 accuracy.

__device__ __forceinline__ void stage_w_slab(_Float16* dsth, _Float16* dstl,
    const _Float16* __restrict__ gh, const _Float16* __restrict__ gl, int stride, int koff) {
  int tid = threadIdx.x;
#pragma unroll
  for (int it = 0; it < 4; ++it) {
    int l = tid + it * 256;
    int r = l >> 3, ch = (l & 7) * 8;
    *(half8*)&dsth[r * PW + ch] = *(const half8*)&gh[(size_t)r * stride + koff + ch];
    *(half8*)&dstl[r * PW + ch] = *(const half8*)&gl[(size_t)r * stride + koff + ch];
  }
}

template <int MF>
__device__ __forceinline__ void gemm_slab(const _Float16* Sh, const _Float16* Sl,
    const _Float16* Wh, const _Float16* Wl, int rowbase, int l15, int l4, int wc, int slab,
    f32x4 (&acc)[MF][4]) {
#pragma unroll
  for (int split = 0; split < 3; ++split) {
    const _Float16* as = (split == 1) ? Sl : Sh;
    const _Float16* bs = (split == 2) ? Wl : Wh;
#pragma unroll
    for (int kf = 0; kf < 2; ++kf) {
      int ka = slab * 64 + kf * 32 + l4 * 8;
      int kw = kf * 32 + l4 * 8;
      half8 a[MF], b[4];
#pragma unroll
      for (int m = 0; m < MF; ++m)
        a[m] = *(const half8*)&as[(rowbase + m * 16 + l15) * PA + ka];
#pragma unroll
      for (int f = 0; f < 4; ++f)
        b[f] = *(const half8*)&bs[(wc * 64 + f * 16 + l15) * PW + kw];
#pragma unroll
      for (int m = 0; m < MF; ++m)
#pragma unroll
        for (int f = 0; f < 4; ++f)
          acc[m][f] = __builtin_amdgcn_mfma_f32_16x16x32_f16(a[m], b[f], acc[m][f], 0, 0, 0);
    }
  }
}

template <int MF, int NH>
__global__ __launch_bounds__(256, 2) void mfma_mlp_kernel(
    float* __restrict__ A, const _Float16* __restrict__ w1hi, const _Float16* __restrict__ w1lo,
    const float* __restrict__ b1, const _Float16* __restrict__ w2hi,
    const _Float16* __restrict__ w2lo, const float* __restrict__ b2,
    float* __restrict__ stats, int N) {
  constexpr int BM = MF * 32;
  __shared__ _Float16 Ab[2][BM * PA];
  __shared__ _Float16 Wb[2][128 * PW];
  __shared__ _Float16 Hb[NH == 2 ? 2 : 1][NH == 2 ? BM * PA : 1];

  const int tid = threadIdx.x;
  const int wave = tid >> 6, lane = tid & 63;
  const int wr = wave >> 1, wc = wave & 1;
  const int l15 = lane & 15, l4 = lane >> 4;
  const int row0 = blockIdx.x * BM;
  const int rowbase = wr * (MF * 16);

  _Float16 *Hh, *Hl;
  if constexpr (NH == 2) { Hh = Hb[0]; Hl = Hb[1]; }
  else { Hh = Ab[0]; Hl = Ab[1]; }

  // ---- stage + hi/lo split of A tile ----
#pragma unroll
  for (int it = 0; it < BM / 8; ++it) {
    int l = tid + it * 256;
    int r = l >> 5, c4 = (l & 31) * 4;
    float4 v = make_float4(0.f, 0.f, 0.f, 0.f);
    if (row0 + r < N) v = *(const float4*)&A[(size_t)(row0 + r) * HDIM + c4];
    half4v hh, ll;
    hh.x = (_Float16)v.x; ll.x = (_Float16)(v.x - (float)hh.x);
    hh.y = (_Float16)v.y; ll.y = (_Float16)(v.y - (float)hh.y);
    hh.z = (_Float16)v.z; ll.z = (_Float16)(v.z - (float)hh.z);
    hh.w = (_Float16)v.w; ll.w = (_Float16)(v.w - (float)hh.w);
    *(half4v*)&Ab[0][r * PA + c4] = hh;
    *(half4v*)&Ab[1][r * PA + c4] = ll;
  }

  f32x4 acc2[MF][4];
#pragma unroll
  for (int f = 0; f < 4; ++f) {
    float bv = b2[wc * 64 + f * 16 + l15];
#pragma unroll
    for (int m = 0; m < MF; ++m) acc2[m][f] = (f32x4){bv, bv, bv, bv};
  }

  for (int h = 0; h < NH; ++h) {
    f32x4 acc1[MF][4];
#pragma unroll
    for (int f = 0; f < 4; ++f) {
      float bv = b1[h * 128 + wc * 64 + f * 16 + l15];
#pragma unroll
      for (int m = 0; m < MF; ++m) acc1[m][f] = (f32x4){bv, bv, bv, bv};
    }
    // GEMM1: A @ W1-half
#pragma unroll
    for (int slab = 0; slab < 2; ++slab) {
      __syncthreads();  // prior W readers done (A staged on first pass)
      stage_w_slab(Wb[0], Wb[1], w1hi + (size_t)h * 128 * 128, w1lo + (size_t)h * 128 * 128,
                   128, slab * 64);
      __syncthreads();
      gemm_slab<MF>(Ab[0], Ab[1], Wb[0], Wb[1], rowbase, l15, l4, wc, slab, acc1);
    }
    __syncthreads();  // all A/W reads done (alias safety for NH==1)
    // ReLU + hi/lo split -> H  (C/D layout: row=(lane>>4)*4+reg, col=lane&15)
#pragma unroll
    for (int m = 0; m < MF; ++m)
#pragma unroll
      for (int f = 0; f < 4; ++f)
#pragma unroll
        for (int r = 0; r < 4; ++r) {
          float v = fmaxf(acc1[m][f][r], 0.f);
          _Float16 hh = (_Float16)v;
          int row = rowbase + m * 16 + l4 * 4 + r;
          int ck = wc * 64 + f * 16 + l15;
          Hh[row * PA + ck] = hh;
          Hl[row * PA + ck] = (_Float16)(v - (float)hh);
        }
    // GEMM2 partial: H @ W2[h*128 : h*128+128, :]
#pragma unroll
    for (int slab = 0; slab < 2; ++slab) {
      __syncthreads();  // H visible, prior W readers done
      stage_w_slab(Wb[0], Wb[1], w2hi, w2lo, NH * 128, h * 128 + slab * 64);
      __syncthreads();
      gemm_slab<MF>(Hh, Hl, Wb[0], Wb[1], rowbase, l15, l4, wc, slab, acc2);
    }
  }

  // ---- epilogue: global store + BN column partials ----
  __syncthreads();  // W readers done; overlay Wb with float partials
  float* psum = (float*)&Wb[0][0];
  float* psq = psum + 256;
#pragma unroll
  for (int f = 0; f < 4; ++f) {
    float s = 0.f, q = 0.f;
#pragma unroll
    for (int m = 0; m < MF; ++m)
#pragma unroll
      for (int r = 0; r < 4; ++r) {
        int grow = row0 + rowbase + m * 16 + l4 * 4 + r;
        float v = acc2[m][f][r];
        if (grow < N) {
          A[(size_t)grow * HDIM + wc * 64 + f * 16 + l15] = v;
          s += v;
          q += v * v;
        }
      }
    s += __shfl_xor(s, 16); q += __shfl_xor(q, 16);
    s += __shfl_xor(s, 32); q += __shfl_xor(q, 32);
    if (l4 == 0) {
      psum[wr * 128 + wc * 64 + f * 16 + l15] = s;
      psq[wr * 128 + wc * 64 + f * 16 + l15] = q;
    }
  }
  __syncthreads();
  if (tid < 128) {
    float S = psum[tid] + psum[128 + tid];
    float Q = psq[tid] + psq[128 + tid];
    atomicAdd(&stats[tid], S);
    atomicAdd(&stats[128 + tid], Q);
  }
}

// ============================ BN finalize + apply ============================
__global__ void bn_finalize_kernel(float* __restrict__ stats, const float* __restrict__ g,
                                   const float* __restrict__ beta, float invN) {
  int c = threadIdx.x;
  if (c < HDIM) {
    float m = stats[c] * invN;
    float v = stats[128 + c] * invN - m * m;
    v = fmaxf(v, 0.f);
    float a = g[c] * rsqrtf(v + BN_EPS_F);
    stats[c] = a;
    stats[128 + c] = beta[c] - m * a;
  }
}

__global__ __launch_bounds__(256) void bn_relu_kernel(float* __restrict__ h,
    const float* __restrict__ stats, const float* __restrict__ identity, int nvec) {
  int i = blockIdx.x * blockDim.x + threadIdx.x;
  int stride = gridDim.x * blockDim.x;
  for (; i < nvec; i += stride) {
    int c4 = (i & 31) * 4;
    float4 x = ((const float4*)h)[i];
    float4 a = *(const float4*)&stats[c4];
    float4 b = *(const float4*)&stats[128 + c4];
    float4 o;
    o.x = fmaxf(fmaf(x.x, a.x, b.x), 0.f);
    o.y = fmaxf(fmaf(x.y, a.y, b.y), 0.f);
    o.z = fmaxf(fmaf(x.z, a.z, b.z), 0.f);
    o.w = fmaxf(fmaf(x.w, a.w, b.w), 0.f);
    if (identity) {
      float4 id = ((const float4*)identity)[i];
      o.x += id.x; o.y += id.y; o.z += id.z; o.w += id.w;
    }
    ((float4*)h)[i] = o;
  }
}

// ============================ Tail (GIN 128->32->3, no BN) ============================
__global__ __launch_bounds__(256, 1) void tail_kernel(
    const float* __restrict__ A, const float* __restrict__ W1, const float* __restrict__ b1,
    const float* __restrict__ W2, const float* __restrict__ b2, float* __restrict__ out, int N) {
  __shared__ float Xs[64][132];
  __shared__ float W1s[128][32];
  __shared__ float H1s[64][36];
  __shared__ float W2s[96];
  __shared__ float b1s[32];
  __shared__ float b2s[3];
  int tid = threadIdx.x;
  int row0 = blockIdx.x * 64;
#pragma unroll
  for (int it = 0; it < 8; ++it) {
    int l = tid + it * 256, r = l >> 5, c4 = l & 31;
    float4 v = make_float4(0.f, 0.f, 0.f, 0.f);
    if (row0 + r < N) v = *(const float4*)&A[(size_t)(row0 + r) * HDIM + c4 * 4];
    *(float4*)&Xs[r][c4 * 4] = v;
  }
#pragma unroll
  for (int it = 0; it < 4; ++it) {
    int l = tid + it * 256;
    int r = l >> 3, c4 = l & 7;
    *(float4*)&W1s[r][c4 * 4] = *(const float4*)&W1[r * 32 + c4 * 4];
  }
  if (tid < 96) W2s[tid] = W2[tid];
  if (tid < 32) b1s[tid] = b1[tid];
  if (tid < 3) b2s[tid] = b2[tid];
  __syncthreads();
  {
    int r = tid >> 2;
    int c0 = (tid & 3) * 8;
    float acc1[8];
#pragma unroll
    for (int j = 0; j < 8; ++j) acc1[j] = b1s[c0 + j];
#pragma unroll 2
    for (int k = 0; k < 128; ++k) {
      float xv = Xs[r][k];
      float4 wA = *(const float4*)&W1s[k][c0];
      float4 wB = *(const float4*)&W1s[k][c0 + 4];
      acc1[0] = fmaf(xv, wA.x, acc1[0]);
      acc1[1] = fmaf(xv, wA.y, acc1[1]);
      acc1[2] = fmaf(xv, wA.z, acc1[2]);
      acc1[3] = fmaf(xv, wA.w, acc1[3]);
      acc1[4] = fmaf(xv, wB.x, acc1[4]);
      acc1[5] = fmaf(xv, wB.y, acc1[5]);
      acc1[6] = fmaf(xv, wB.z, acc1[6]);
      acc1[7] = fmaf(xv, wB.w, acc1[7]);
    }
#pragma unroll
    for (int j = 0; j < 8; ++j) H1s[r][c0 + j] = fmaxf(acc1[j], 0.f);
  }
  __syncthreads();
  if (tid < 192) {
    int r = tid / 3, c = tid - (tid / 3) * 3;
    float accv = b2s[c];
#pragma unroll
    for (int k = 0; k < 32; ++k) accv = fmaf(H1s[r][k], W2s[k * 3 + c], accv);
    if (row0 + r < N) out[(size_t)(row0 + r) * 3 + c] = accv;
  }
}

// ============================ Host launcher ============================
extern "C" void kernel_launch(void* const* d_in, const int* in_sizes, int n_in,
                              void* d_out, int out_size, void* d_ws, size_t ws_size,
                              hipStream_t stream) {
  const float* x = (const float*)d_in[0];
  const int* ei = (const int*)d_in[1];
  const float* head_w1 = (const float*)d_in[2];
  const float* head_b1 = (const float*)d_in[3];
  const float* head_w2 = (const float*)d_in[4];
  const float* head_b2 = (const float*)d_in[5];
  const float* head_g = (const float*)d_in[6];
  const float* head_bt = (const float*)d_in[7];
  const float* res_w1 = (const float*)d_in[8];
  const float* res_b1 = (const float*)d_in[9];
  const float* res_w2 = (const float*)d_in[10];
  const float* res_b2 = (const float*)d_in[11];
  const float* res_g = (const float*)d_in[12];
  const float* res_bt = (const float*)d_in[13];
  const float* tail_w1 = (const float*)d_in[14];
  const float* tail_b1 = (const float*)d_in[15];
  const float* tail_w2 = (const float*)d_in[16];
  const float* tail_b2 = (const float*)d_in[17];

  const int N = in_sizes[0] / HDIM;
  const int E = in_sizes[1] / 2;
  const int* srcp = ei;
  const int* dstp = ei + E;

  char* base = (char*)d_ws;
  size_t off = 0;
  auto alloc = [&](size_t bytes) -> void* {
    void* p = base + off;
    off += (bytes + 255) & ~(size_t)255;
    return p;
  };
  float* p0 = (float*)alloc((size_t)N * HDIM * 4);
  float* p1 = (float*)alloc((size_t)N * HDIM * 4);
  float* p2 = (float*)alloc((size_t)N * HDIM * 4);
  int* cnt = (int*)alloc((size_t)N * 4);
  int* pos = (int*)alloc((size_t)N * 4);
  int* rowptr = (int*)alloc((size_t)(N + 1) * 4);
  int* colb = (int*)alloc((size_t)E * 4);
  const int NB = (N + SCAN_CHUNK - 1) / SCAN_CHUNK;
  int* bsum = (int*)alloc((size_t)NB * 4);
  float* stats = (float*)alloc(256 * 4);
  // f16 hi/lo transposed weights: head_w1t(256x128)=32768, head_w2t(128x256)=32768,
  // res u: w1t at 65536+u*32768, w2t at +16384
  _Float16* whi = (_Float16*)alloc(262144 * 2);
  _Float16* wlo = (_Float16*)alloc(262144 * 2);
  (void)ws_size; (void)n_in; (void)out_size;

  // ---- weight prep (transpose + f16 hi/lo split) ----
  auto wprep = [&](const float* W, _Float16* hi, _Float16* lo, int K, int Nn) {
    int total = K * Nn;
    wprep_kernel<<<(total + 255) / 256, 256, 0, stream>>>(W, hi, lo, K, Nn);
  };
  wprep(head_w1, whi, wlo, 128, 256);
  wprep(head_w2, whi + 32768, wlo + 32768, 256, 128);
  for (int u = 0; u < 6; ++u) {
    wprep(res_w1 + (size_t)u * 16384, whi + 65536 + u * 32768, wlo + 65536 + u * 32768, 128, 128);
    wprep(res_w2 + (size_t)u * 16384, whi + 65536 + u * 32768 + 16384,
          wlo + 65536 + u * 32768 + 16384, 128, 128);
  }

  // ---- CSR build (edge structure shared by all 8 layers) ----
  hipMemsetAsync(cnt, 0, (size_t)N * 4, stream);
  hist_kernel<<<2048, 256, 0, stream>>>(dstp, E, cnt);
  scan_phase1<<<NB, SCAN_T, 0, stream>>>(cnt, N, bsum);
  scan_phase2<<<1, 64, 0, stream>>>(bsum, NB, rowptr, N);
  scan_phase3<<<NB, SCAN_T, 0, stream>>>(cnt, N, bsum, rowptr, pos);
  fill_kernel<<<2048, 256, 0, stream>>>(srcp, dstp, E, pos, colb);

  const int aggGrid = (N + 3) / 4;
  const float invN = 1.0f / (float)N;

  // ---- head: GIN(128->256->128) + BN + ReLU ----
  aggregate_kernel<<<aggGrid, 256, 0, stream>>>(x, p0, rowptr, colb, N);
  hipMemsetAsync(stats, 0, 256 * 4, stream);
  mfma_mlp_kernel<1, 2><<<(N + 31) / 32, 256, 0, stream>>>(
      p0, whi, wlo, head_b1, whi + 32768, wlo + 32768, head_b2, stats, N);
  bn_finalize_kernel<<<1, 128, 0, stream>>>(stats, head_g, head_bt, invN);
  bn_relu_kernel<<<2048, 256, 0, stream>>>(p0, stats, (const float*)nullptr, N * (HDIM / 4));

  // ---- residual blocks ----
  auto res_unit = [&](float* bin, float* bout, int u, const float* ident) {
    aggregate_kernel<<<aggGrid, 256, 0, stream>>>(bin, bout, rowptr, colb, N);
    hipMemsetAsync(stats, 0, 256 * 4, stream);
    mfma_mlp_kernel<2, 1><<<(N + 63) / 64, 256, 0, stream>>>(
        bout, whi + 65536 + u * 32768, wlo + 65536 + u * 32768, res_b1 + (size_t)u * HDIM,
        whi + 65536 + u * 32768 + 16384, wlo + 65536 + u * 32768 + 16384,
        res_b2 + (size_t)u * HDIM, stats, N);
    bn_finalize_kernel<<<1, 128, 0, stream>>>(stats, res_g + (size_t)u * HDIM,
                                              res_bt + (size_t)u * HDIM, invN);
    bn_relu_kernel<<<2048, 256, 0, stream>>>(bout, stats, ident, N * (HDIM / 4));
  };
  res_unit(p0, p1, 0, nullptr);
  res_unit(p1, p2, 1, p0);
  res_unit(p2, p0, 2, nullptr);
  res_unit(p0, p1, 3, p2);
  res_unit(p1, p2, 4, nullptr);
  res_unit(p2, p0, 5, p1);

  // ---- tail: GIN(128->32->3), no BN ----
  aggregate_kernel<<<aggGrid, 256, 0, stream>>>(p0, p1, rowptr, colb, N);
  tail_kernel<<<(N + 63) / 64, 256, 0, stream>>>(p1, tail_w1, tail_b1, tail_w2, tail_b2,
                                                 (float*)d_out, N);
}